// Round 2
// baseline (118.734 us; speedup 1.0000x reference)
//
#include <hip/hip_runtime.h>

typedef unsigned short u16;
typedef short short8 __attribute__((ext_vector_type(8)));
typedef float floatx4 __attribute__((ext_vector_type(4)));
typedef unsigned int uintx4 __attribute__((ext_vector_type(4)));
typedef u16 ushortx4 __attribute__((ext_vector_type(4)));

#define FEAT 1024
#define KNB  32

__device__ __forceinline__ float bf2f(u16 b) { return __uint_as_float(((unsigned)b) << 16); }
__device__ __forceinline__ u16 f2bf(float f) {
    unsigned u = __float_as_uint(f);
    u += 0x7fffu + ((u >> 16) & 1u);
    return (u16)(u >> 16);
}
__device__ __forceinline__ unsigned pack2bf(float a, float b) {
    return (unsigned)f2bf(a) | ((unsigned)f2bf(b) << 16);
}

union Frag { uintx4 q; unsigned d[4]; short8 v; };

// ---------------------------------------------------------------------------
// K0: zero the atomic partial buffer pws[64][33][64] f32
// ---------------------------------------------------------------------------
__global__ void k0_zero(float* __restrict__ pws) {
    int idx = blockIdx.x * 256 + threadIdx.x;
    if (idx < 64 * 33 * 64) pws[idx] = 0.f;
}

// ---------------------------------------------------------------------------
// K2: layer-1 main kernel (f32 inputs).
// grid = 512 (node*8 + a-chunk), block = 256 (4 waves).
// Z[a, j] = sum_b sign(x_a*S_b + x_b*S_a) * Y[j][b],  Y = [x, nb0..nb31]
// epilogue: pws[n][j][o] += sum_{a in chunk} Z[a,j] * W1[o,a]  (atomic f32)
// ---------------------------------------------------------------------------
__global__ __launch_bounds__(256, 2) void k2_main(
    const float* __restrict__ xg, const float* __restrict__ nbg,
    const float* __restrict__ w1g, float* __restrict__ pws)
{
    __shared__ float sS[FEAT];          // 4 KB   S[b] = sum_k nb[n][k][b]
    __shared__ u16  sY[33 * 512];       // 33.8 KB bf16 half-rows of Y; reused as Z

    const int t = threadIdx.x;
    const int n = blockIdx.x >> 3;
    const int chunk = blockIdx.x & 7;
    const int chunkbase = chunk * 128;
    const int w = t >> 6;       // wave 0..3
    const int l = t & 63;
    const int m = l & 15;       // MFMA row/col-in-tile
    const int g = l >> 4;       // quad (k-group)

    // ---- S[b] (f32), coalesced: thread t owns cols 4t..4t+3 ----
    {
        const float* base = nbg + ((size_t)n * KNB) * FEAT + t * 4;
        floatx4 a = {0.f, 0.f, 0.f, 0.f};
        #pragma unroll 4
        for (int k = 0; k < KNB; ++k) {
            floatx4 qq = *(const floatx4*)(base + k * FEAT);
            a += qq;
        }
        *(floatx4*)&sS[t * 4] = a;
    }

    floatx4 acc[2][3];
    #pragma unroll
    for (int i = 0; i < 2; ++i)
        #pragma unroll
        for (int j = 0; j < 3; ++j) { floatx4 z = {0.f,0.f,0.f,0.f}; acc[i][j] = z; }

    // per-lane A-side constants (a = chunkbase + w*32 + tile*16 + m)
    float xa0 = xg[(size_t)n * FEAT + chunkbase + w*32 + m];
    float xa1 = xg[(size_t)n * FEAT + chunkbase + w*32 + 16 + m];
    float Sa0 = 0.f, Sa1 = 0.f;

    for (int h = 0; h < 2; ++h) {
        if (h) __syncthreads();   // protect sY from previous half's readers
        // ---- stage Y half h as bf16: 33 rows x 512 cols, 16B-chunk swizzle c^(j&7) ----
        for (int r = 0; r < 9; ++r) {
            int cc = t + r * 256;
            if (cc < 33 * 64) {
                int j = cc >> 6, c = cc & 63;
                const float* src = (j == 0 ? xg + (size_t)n * FEAT
                                           : nbg + ((size_t)n * KNB + (j - 1)) * FEAT)
                                   + h * 512 + c * 8;
                floatx4 f0 = *(const floatx4*)src;
                floatx4 f1 = *(const floatx4*)(src + 4);
                uintx4 vv;
                vv.x = pack2bf(f0[0], f0[1]);
                vv.y = pack2bf(f0[2], f0[3]);
                vv.z = pack2bf(f1[0], f1[1]);
                vv.w = pack2bf(f1[2], f1[3]);
                *(uintx4*)&sY[j * 512 + ((c ^ (j & 7)) * 8)] = vv;
            }
        }
        __syncthreads();
        if (h == 0) {
            Sa0 = sS[chunkbase + w*32 + m];
            Sa1 = sS[chunkbase + w*32 + 16 + m];
        }

        // ---- 16 K-steps (K=32 each) over this half ----
        for (int s = 0; s < 16; ++s) {
            const int bloc = s * 32 + g * 8;   // local b of this lane's 8 entries
            const int c = bloc >> 3;           // 16B chunk index (row-0 swizzle = identity)
            Frag xbf; xbf.q = *(const uintx4*)&sY[c * 8];
            float xb[8];
            #pragma unroll
            for (int i = 0; i < 4; ++i) {
                xb[2*i]   = bf2f((u16)(xbf.d[i] & 0xffffu));
                xb[2*i+1] = bf2f((u16)(xbf.d[i] >> 16));
            }
            floatx4 sb0 = *(const floatx4*)&sS[h * 512 + bloc];
            floatx4 sb1 = *(const floatx4*)&sS[h * 512 + bloc + 4];
            float Sb[8] = {sb0[0],sb0[1],sb0[2],sb0[3],sb1[0],sb1[1],sb1[2],sb1[3]};

            // A-frags: sign(u) packed as bf16 +-1.0
            Frag af0, af1;
            #pragma unroll
            for (int p = 0; p < 4; ++p) {
                float u0 = fmaf(xa0, Sb[2*p],   xb[2*p]   * Sa0);
                float u1 = fmaf(xa0, Sb[2*p+1], xb[2*p+1] * Sa0);
                af0.d[p] = 0x3F803F80u | (__float_as_uint(u1) & 0x80000000u)
                                       | ((__float_as_uint(u0) >> 16) & 0x8000u);
                float v0 = fmaf(xa1, Sb[2*p],   xb[2*p]   * Sa1);
                float v1 = fmaf(xa1, Sb[2*p+1], xb[2*p+1] * Sa1);
                af1.d[p] = 0x3F803F80u | (__float_as_uint(v1) & 0x80000000u)
                                       | ((__float_as_uint(v0) >> 16) & 0x8000u);
            }

            // B-frags: lane holds Y[j = tile*16 + m][bloc..bloc+7]
            const int sw = (m & 7) * 8;
            Frag b0, b1, b2;
            b0.q = *(const uintx4*)&sY[ m       * 512 + ((c * 8) ^ sw)];
            b1.q = *(const uintx4*)&sY[(16 + m) * 512 + ((c * 8) ^ sw)];
            b2.q = *(const uintx4*)&sY[ 32      * 512 + c * 8];   // row 32 (nb31), swizzle 0
            if (m != 0) { b2.d[0] = 0; b2.d[1] = 0; b2.d[2] = 0; b2.d[3] = 0; }  // j>32 -> 0

            acc[0][0] = __builtin_amdgcn_mfma_f32_16x16x32_bf16(af0.v, b0.v, acc[0][0], 0, 0, 0);
            acc[0][1] = __builtin_amdgcn_mfma_f32_16x16x32_bf16(af0.v, b1.v, acc[0][1], 0, 0, 0);
            acc[0][2] = __builtin_amdgcn_mfma_f32_16x16x32_bf16(af0.v, b2.v, acc[0][2], 0, 0, 0);
            acc[1][0] = __builtin_amdgcn_mfma_f32_16x16x32_bf16(af1.v, b0.v, acc[1][0], 0, 0, 0);
            acc[1][1] = __builtin_amdgcn_mfma_f32_16x16x32_bf16(af1.v, b1.v, acc[1][1], 0, 0, 0);
            acc[1][2] = __builtin_amdgcn_mfma_f32_16x16x32_bf16(af1.v, b2.v, acc[1][2], 0, 0, 0);
        }
    }
    __syncthreads();

    // ---- write Z (bf16) to LDS, layout [j 48][a 128] stride 136 ----
    u16* sZ = sY;
    #pragma unroll
    for (int ti = 0; ti < 2; ++ti)
        #pragma unroll
        for (int jt = 0; jt < 3; ++jt) {
            int j = jt * 16 + m;                  // C col = j
            int aloc = w * 32 + ti * 16 + g * 4;  // C rows = 4 consecutive a
            ushortx4 zz;
            zz.x = f2bf(acc[ti][jt][0]);
            zz.y = f2bf(acc[ti][jt][1]);
            zz.z = f2bf(acc[ti][jt][2]);
            zz.w = f2bf(acc[ti][jt][3]);
            *(ushortx4*)&sZ[j * 136 + aloc] = zz;
        }
    __syncthreads();

    // ---- epilogue: pws[n][j][o] += sum_{a in chunk} Z[a,j] * W1[o,a] via MFMA ----
    floatx4 a2[3];
    #pragma unroll
    for (int j = 0; j < 3; ++j) { floatx4 z = {0.f,0.f,0.f,0.f}; a2[j] = z; }
    #pragma unroll
    for (int kc = 0; kc < 4; ++kc) {
        const float* wsrc = w1g + (size_t)(w * 16 + m) * FEAT + chunkbase + kc * 32 + g * 8;
        floatx4 wf0 = *(const floatx4*)wsrc;
        floatx4 wf1 = *(const floatx4*)(wsrc + 4);
        Frag wb;
        wb.d[0] = pack2bf(wf0[0], wf0[1]);
        wb.d[1] = pack2bf(wf0[2], wf0[3]);
        wb.d[2] = pack2bf(wf1[0], wf1[1]);
        wb.d[3] = pack2bf(wf1[2], wf1[3]);
        #pragma unroll
        for (int jt = 0; jt < 3; ++jt) {
            Frag za;
            za.q = *(const uintx4*)&sZ[(jt * 16 + m) * 136 + kc * 32 + g * 8];
            a2[jt] = __builtin_amdgcn_mfma_f32_16x16x32_bf16(za.v, wb.v, a2[jt], 0, 0, 0);
        }
    }
    float* pbase = pws + (size_t)n * 33 * 64;
    #pragma unroll
    for (int jt = 0; jt < 3; ++jt)
        #pragma unroll
        for (int r = 0; r < 4; ++r) {
            int j = jt * 16 + g * 4 + r;
            if (j < 33) atomicAdd(&pbase[j * 64 + w * 16 + m], a2[jt][r]);
        }
}

// ---------------------------------------------------------------------------
// K3b: x-path BN (stats per channel over nodes+features) + softsign -> x1
// ---------------------------------------------------------------------------
__global__ __launch_bounds__(256) void k3_bnx(
    const float* __restrict__ pws, const float* __restrict__ bn1w,
    const float* __restrict__ bn1b, float* __restrict__ x1ws)
{
    __shared__ float sx2[64 * 64];
    __shared__ float ssc[4], sbi[4];
    const int t = threadIdx.x;
    #pragma unroll
    for (int r = 0; r < 16; ++r) {
        int idx = t + r * 256;               // n*64 + o
        int nn = idx >> 6, o = idx & 63;
        sx2[idx] = pws[(size_t)nn * 2112 + o];
    }
    __syncthreads();
    {
        int cc = t >> 6, l2 = t & 63;        // wave cc reduces channel cc
        float s = 0.f, s2 = 0.f;
        #pragma unroll
        for (int i = 0; i < 16; ++i) {
            int idx = l2 * 16 + i;           // 0..1023 -> (n, f)
            int nn = idx >> 4, f = idx & 15;
            float v = sx2[nn * 64 + cc * 16 + f];
            s += v; s2 += v * v;
        }
        #pragma unroll
        for (int off = 32; off > 0; off >>= 1) {
            s  += __shfl_down(s, off);
            s2 += __shfl_down(s2, off);
        }
        if (l2 == 0) {
            float mean = s * (1.f / 1024.f);
            float var = s2 * (1.f / 1024.f) - mean * mean;
            float rs = rsqrtf(var + 1e-5f);
            float wv = bn1w[cc], bv = bn1b[cc];
            ssc[cc] = rs * wv;
            sbi[cc] = bv - mean * rs * wv;
        }
    }
    __syncthreads();
    #pragma unroll
    for (int r = 0; r < 16; ++r) {
        int idx = t + r * 256;
        int o = idx & 63, cc = o >> 4;
        float v = sx2[idx] * ssc[cc] + sbi[cc];
        x1ws[idx] = v / (1.f + fabsf(v));
    }
}

// ---------------------------------------------------------------------------
// K3c: per-node: nb BN (per n,c over k,f) + softsign -> S1; exact layer-2
// adjacency (channel-coupled denominator); xa2; W2 contraction -> x2_2
// ---------------------------------------------------------------------------
__global__ __launch_bounds__(256) void k3_node(
    const float* __restrict__ pws, const float* __restrict__ x1ws,
    const float* __restrict__ bn1w, const float* __restrict__ bn1b,
    const float* __restrict__ w2g, float* __restrict__ x22ws)
{
    __shared__ float snb[32 * 64];           // [k][o]
    __shared__ float sx1[64], sS1[64], sadj[4 * 16 * 16], sxa[64];
    __shared__ float ssc[4], sbi[4];
    const int t = threadIdx.x;
    const int n = blockIdx.x;

    #pragma unroll
    for (int r = 0; r < 8; ++r) {
        int idx = t + r * 256;               // k*64 + o
        int k = idx >> 6, o = idx & 63;
        snb[idx] = pws[(size_t)n * 2112 + (1 + k) * 64 + o];
    }
    if (t < 64) sx1[t] = x1ws[n * 64 + t];
    __syncthreads();
    {
        int cc = t >> 6, l2 = t & 63;
        float s = 0.f, s2 = 0.f;
        #pragma unroll
        for (int i = 0; i < 8; ++i) {
            int idx = l2 * 8 + i;            // 0..511 -> (k, f)
            int k = idx >> 4, f = idx & 15;
            float v = snb[k * 64 + cc * 16 + f];
            s += v; s2 += v * v;
        }
        #pragma unroll
        for (int off = 32; off > 0; off >>= 1) {
            s  += __shfl_down(s, off);
            s2 += __shfl_down(s2, off);
        }
        if (l2 == 0) {
            float mean = s * (1.f / 512.f);
            float var = s2 * (1.f / 512.f) - mean * mean;
            float rs = rsqrtf(var + 1e-5f);
            float wv = bn1w[cc], bv = bn1b[cc];
            ssc[cc] = rs * wv;
            sbi[cc] = bv - mean * rs * wv;
        }
    }
    __syncthreads();
    if (t < 64) {                            // S1[c*16+f] = sum_k softsign(bn(nb2))
        int cc = t >> 4;
        float a = 0.f;
        for (int k = 0; k < 32; ++k) {
            float v = snb[k * 64 + t] * ssc[cc] + sbi[cc];
            a += v / (1.f + fabsf(v));
        }
        sS1[t] = a;
    }
    __syncthreads();
    {
        int a = t >> 4, b = t & 15;          // one (a,b) pair per thread
        float sc[4]; float den = 1e-7f;
        #pragma unroll
        for (int c = 0; c < 4; ++c) {
            float u = sx1[c * 16 + a] * sS1[c * 16 + b] + sx1[c * 16 + b] * sS1[c * 16 + a];
            float r = sqrtf(fmaxf(fabsf(u), 1e-8f));
            sc[c] = copysignf(r, u);
            den += r;
        }
        float inv = 1.f / den;
        #pragma unroll
        for (int c = 0; c < 4; ++c) sadj[(c * 16 + a) * 16 + b] = sc[c] * inv;
    }
    __syncthreads();
    if (t < 64) {                            // xa2[c][a] = sum_b adj2 * x1
        int cc = t >> 4;
        float a = 0.f;
        #pragma unroll
        for (int b = 0; b < 16; ++b) a += sadj[t * 16 + b] * sx1[cc * 16 + b];
        sxa[t] = a;
    }
    __syncthreads();
    if (t < 32) {                            // x2_2[o] = sum_{c,f} W2[o][c][f] * xa2
        float a = 0.f;
        #pragma unroll
        for (int cf = 0; cf < 64; ++cf) a += w2g[t * 64 + cf] * sxa[cf];
        x22ws[n * 32 + t] = a;
    }
}

// ---------------------------------------------------------------------------
// K3d: BN2 (per o over nodes) + softsign + linear head -> f32 logits
// ---------------------------------------------------------------------------
__global__ __launch_bounds__(256) void k3_fin(
    const float* __restrict__ x22ws, const float* __restrict__ bn2w,
    const float* __restrict__ bn2b, const float* __restrict__ linw,
    const float* __restrict__ linb, float* __restrict__ outg)
{
    __shared__ float sx[64 * 32];
    __shared__ float sy[64 * 32];
    __shared__ float ssc[32], sbi[32];
    const int t = threadIdx.x;
    #pragma unroll
    for (int r = 0; r < 8; ++r) sx[t + r * 256] = x22ws[t + r * 256];
    __syncthreads();
    if (t < 32) {
        float s = 0.f, s2 = 0.f;
        for (int nn = 0; nn < 64; ++nn) {
            float v = sx[nn * 32 + t];
            s += v; s2 += v * v;
        }
        float mean = s * (1.f / 64.f);
        float var = s2 * (1.f / 64.f) - mean * mean;
        float rs = rsqrtf(var + 1e-5f);
        float wv = bn2w[t], bv = bn2b[t];
        ssc[t] = rs * wv;
        sbi[t] = bv - mean * rs * wv;
    }
    __syncthreads();
    #pragma unroll
    for (int r = 0; r < 8; ++r) {
        int idx = t + r * 256;
        int o = idx & 31;
        float v = sx[idx] * ssc[o] + sbi[o];
        sy[idx] = v / (1.f + fabsf(v));
    }
    __syncthreads();
    for (int r = 0; r < 3; ++r) {
        int idx = t + r * 256;
        if (idx < 640) {
            int nn = idx / 10, cls = idx % 10;
            float a = linb[cls];
            #pragma unroll
            for (int o = 0; o < 32; ++o) a += sy[nn * 32 + o] * linw[cls * 32 + o];
            outg[idx] = a;
        }
    }
}

extern "C" void kernel_launch(void* const* d_in, const int* in_sizes, int n_in,
                              void* d_out, int out_size, void* d_ws, size_t ws_size,
                              hipStream_t stream) {
    (void)in_sizes; (void)n_in; (void)out_size; (void)ws_size;
    const float* xg   = (const float*)d_in[0];
    const float* nbg  = (const float*)d_in[1];
    const float* w1g  = (const float*)d_in[2];
    const float* w2g  = (const float*)d_in[3];
    const float* bn1w = (const float*)d_in[4];
    const float* bn1b = (const float*)d_in[5];
    const float* bn2w = (const float*)d_in[6];
    const float* bn2b = (const float*)d_in[7];
    const float* linw = (const float*)d_in[8];
    const float* linb = (const float*)d_in[9];

    float* pws   = (float*)d_ws;                   // [64][33][64] f32, atomic-reduced
    float* x1ws  = pws + (size_t)64 * 33 * 64;     // [64][64]
    float* x22ws = x1ws + 64 * 64;                 // [64][32]
    float* outg  = (float*)d_out;

    k0_zero<<<dim3(528), dim3(256), 0, stream>>>(pws);
    k2_main<<<dim3(512), dim3(256), 0, stream>>>(xg, nbg, w1g, pws);
    k3_bnx<<<dim3(1), dim3(256), 0, stream>>>(pws, bn1w, bn1b, x1ws);
    k3_node<<<dim3(64), dim3(256), 0, stream>>>(pws, x1ws, bn1w, bn1b, w2g, x22ws);
    k3_fin<<<dim3(1), dim3(256), 0, stream>>>(x22ws, bn2w, bn2b, linw, linb, outg);
}